// Round 5
// baseline (472.397 us; speedup 1.0000x reference)
//
#include <hip/hip_runtime.h>
#include <math.h>

typedef __attribute__((ext_vector_type(8))) __bf16 bf16x8;
typedef __attribute__((ext_vector_type(4))) float f32x4;
typedef __attribute__((ext_vector_type(16))) float f32x16;
typedef __attribute__((ext_vector_type(8))) unsigned short u16x8;
typedef __attribute__((ext_vector_type(8))) int i32x8;

#define GAS(p) ((const __attribute__((address_space(1))) void*)(p))
#define LAS(p) ((__attribute__((address_space(3))) void*)(p))

__device__ __forceinline__ unsigned short f2bf(float f) {
  union { float f; unsigned int u; } v; v.f = f;
  unsigned int r = (v.u + 0x7FFFu + ((v.u >> 16) & 1u)) >> 16;
  return (unsigned short)r;
}
__device__ __forceinline__ float bf2f(unsigned short b) {
  union { unsigned int u; float f; } v; v.u = ((unsigned int)b) << 16;
  return v.f;
}

// ---------------- fused f32 -> bf16 cast for z1,z2,w1,w2 ----------------
__global__ __launch_bounds__(256) void cast_all_kernel(
    const float* __restrict__ z1, const float* __restrict__ z2,
    const float* __restrict__ w1, const float* __restrict__ w2,
    unsigned short* __restrict__ z1b, unsigned short* __restrict__ z2b,
    unsigned short* __restrict__ w1b, unsigned short* __restrict__ w2b) {
  int b = blockIdx.x;
  const float* in; unsigned short* out; int base;
  if (b < 4096)       { in = z1; out = z1b; base = b; }
  else if (b < 8192)  { in = z2; out = z2b; base = b - 4096; }
  else if (b < 8448)  { in = w1; out = w1b; base = b - 8192; }
  else                { in = w2; out = w2b; base = b - 8448; }
  int i = (base * 256 + threadIdx.x) * 4;
  float4 v = *(const float4*)(in + i);
  ushort4 o;
  o.x = f2bf(v.x); o.y = f2bf(v.y); o.z = f2bf(v.z); o.w = f2bf(v.w);
  *(ushort4*)(out + i) = o;
}

// ------ 128x128 NT bf16 tile, K=512, DOUBLE-BUFFERED K=32 chunks ------
__device__ __forceinline__ void gemm_tile_512_db(
    const unsigned short* __restrict__ A, const unsigned short* __restrict__ B,
    int m0, int n0, unsigned short* lA, unsigned short* lB, f32x4 acc[4][4]) {
  constexpr int K = 512;
  const int tid  = threadIdx.x;
  const int wave = tid >> 6;
  const int lane = tid & 63;
  const int quad = lane >> 4;
  const int l16  = lane & 15;
  const int wrow = (wave & 1) * 64;
  const int wcol = (wave >> 1) * 64;

  const f32x4 zero = {0.f, 0.f, 0.f, 0.f};
#pragma unroll
  for (int i = 0; i < 4; ++i)
#pragma unroll
    for (int j = 0; j < 4; ++j) acc[i][j] = zero;

  const int e0 = wave * 1024 + lane * 8;    // element in 4096-elem buffer
  const int r0 = e0 >> 5, c0 = e0 & 31;
  const int e1 = e0 + 512;
  const int r1 = e1 >> 5, c1 = e1 & 31;

  const unsigned short* Ag0 = A + (size_t)(m0 + r0) * K + c0;
  const unsigned short* Ag1 = A + (size_t)(m0 + r1) * K + c1;
  const unsigned short* Bg0 = B + (size_t)(n0 + r0) * K + c0;
  const unsigned short* Bg1 = B + (size_t)(n0 + r1) * K + c1;

  // prologue: stage chunk 0 into buffer 0
  __builtin_amdgcn_global_load_lds(GAS(Ag0), LAS(&lA[e0]), 16, 0, 0);
  __builtin_amdgcn_global_load_lds(GAS(Ag1), LAS(&lA[e1]), 16, 0, 0);
  __builtin_amdgcn_global_load_lds(GAS(Bg0), LAS(&lB[e0]), 16, 0, 0);
  __builtin_amdgcn_global_load_lds(GAS(Bg1), LAS(&lB[e1]), 16, 0, 0);
  __syncthreads();

  for (int kt = 0; kt < 16; ++kt) {
    const int cur = (kt & 1) * 4096;
    if (kt < 15) {
      const int nxt = 4096 - cur;
      const int ko = (kt + 1) * 32;
      __builtin_amdgcn_global_load_lds(GAS(Ag0 + ko), LAS(&lA[nxt + e0]), 16, 0, 0);
      __builtin_amdgcn_global_load_lds(GAS(Ag1 + ko), LAS(&lA[nxt + e1]), 16, 0, 0);
      __builtin_amdgcn_global_load_lds(GAS(Bg0 + ko), LAS(&lB[nxt + e0]), 16, 0, 0);
      __builtin_amdgcn_global_load_lds(GAS(Bg1 + ko), LAS(&lB[nxt + e1]), 16, 0, 0);
    }
    bf16x8 af[4], bfr[4];
#pragma unroll
    for (int i = 0; i < 4; ++i) {
      af[i]  = *(const bf16x8*)&lA[cur + (wrow + i * 16 + l16) * 32 + quad * 8];
      bfr[i] = *(const bf16x8*)&lB[cur + (wcol + i * 16 + l16) * 32 + quad * 8];
    }
#pragma unroll
    for (int mi = 0; mi < 4; ++mi)
#pragma unroll
      for (int ni = 0; ni < 4; ++ni)
        acc[mi][ni] = __builtin_amdgcn_mfma_f32_16x16x32_bf16(
            af[mi], bfr[ni], acc[mi][ni], 0, 0, 0);
    __syncthreads();   // drains this iter's prefetch (mostly done) + WAR
  }
}

// ---------------- fused projection GEMM (2 inputs per launch) ----------------
template<int EPI>
__global__ __launch_bounds__(256)
void proj_kernel(const unsigned short* __restrict__ A1,
                 const unsigned short* __restrict__ A2,
                 const unsigned short* __restrict__ W,
                 const float* __restrict__ bias,
                 unsigned short* __restrict__ C1,
                 unsigned short* __restrict__ C2) {
  __shared__ unsigned short lA[2 * 128 * 32];
  __shared__ unsigned short lB[2 * 128 * 32];
  const int b = blockIdx.x;
  const int which = b >> 8;
  const int r = b & 255;
  const int n0 = (r & 3) * 128;
  const int m0 = (r >> 2) * 128;
  const unsigned short* A = which ? A2 : A1;
  unsigned short* C = which ? C2 : C1;

  f32x4 acc[4][4];
  gemm_tile_512_db(A, W, m0, n0, lA, lB, acc);

  const int lane = threadIdx.x & 63;
  const int wave = threadIdx.x >> 6;
  const int quad = lane >> 4;
  const int l16  = lane & 15;
  const int wrow = (wave & 1) * 64;
  const int wcol = (wave >> 1) * 64;

#pragma unroll
  for (int ni = 0; ni < 4; ++ni) {
    const int c = n0 + wcol + ni * 16 + l16;
    const float bv = bias[c];
#pragma unroll
    for (int mi = 0; mi < 4; ++mi) {
      const int rbase = m0 + wrow + mi * 16 + quad * 4;
#pragma unroll
      for (int rr = 0; rr < 4; ++rr) {
        float v = acc[mi][ni][rr] + bv;
        if constexpr (EPI == 0) v = (v > 0.f) ? v : expm1f(v);
        C[(size_t)(rbase + rr) * 512 + c] = f2bf(v);
      }
    }
  }
}

// ========== R11 gram + depth-2 B register pipeline (ILP, not TLP) ==========
// R12-R14 lesson: the gram wave needs ~190 unified regs (64 AGPR acc incl.),
// so >=4 waves/SIMD (128-reg cap) ALWAYS spills (WRITE_SIZE 230 MB), and
// launch_bounds' 2nd arg is waves/EU -- (512,4) was a 128 cap, not 512.
// TLP is capped at 2 waves/SIMD. This round keeps R11 EXACTLY (block map,
// A staging, per-wave 64x64 quadrant, (256,2)) and adds ILP: the 8 K-steps
// per tile are software-pipelined with a 4-buffer B-fragment rotation,
// prefetch distance 2 (~320-400 cyc of issue between load and use >= L2
// latency ~200), with cross-tile prefetch in steps 6/7 so the exp epilogue
// overlaps the next tile's loads. All buffer indices compile-time (rule #20).
// Block map: [0,544) tri1 (q1,d11), [544,1088) tri2 (q2,d22),
//            [1088,2112) cross (q1 x q2 -> d12r/d12c), b=1088+g*64+row.
// Tri rows in quads: rows 4q..4q+3 have q+1 groups; cum = 2q(q+1).
__global__ __launch_bounds__(256, 2)
void gram_kernel(const unsigned char* __restrict__ q1,
                 const unsigned char* __restrict__ q2,
                 float* __restrict__ d11, float* __restrict__ d22,
                 float* __restrict__ d12r, float* __restrict__ d12c) {
  __shared__ unsigned char lA[65536];   // 4 panels x full K (fragment-major)

  const int b = blockIdx.x;
  const unsigned char *Abase, *Bbase;
  float *rptr, *cptr;
  int by, g, cnt;
  bool cross;
  if (b < 1088) {
    const bool first = (b < 544);
    int j = first ? b : b - 544;
    int q = (int)((sqrtf(2.f * j + 1.f) - 1.f) * 0.5f);
    while (2 * (q + 1) * (q + 2) <= j) ++q;
    while (2 * q * (q + 1) > j) --q;
    const int w = j - 2 * q * (q + 1);
    const int dr = w / (q + 1);
    g = w - dr * (q + 1);
    by = 4 * q + dr;
    const unsigned char* h = first ? q1 : q2;
    Abase = h; Bbase = h;
    rptr = first ? d11 : d22; cptr = rptr;
    cnt = min(4, by + 1 - g * 4);
    cross = false;
  } else {
    const int j = b - 1088;
    g = j >> 6; by = j & 63;
    Abase = q1; Bbase = q2;
    rptr = d12r; cptr = d12c;
    cnt = 4; cross = true;
  }

  const int tid  = threadIdx.x;
  const int wave = tid >> 6;
  const int lane = tid & 63;
  const int half = lane >> 5;
  const int l31  = lane & 31;
  const int pa0 = (wave & 1) * 2;
  const int pb0 = (wave >> 1) * 2;
  const int lfo = half * 1024 + l31 * 16;

  // ---- stage the full A tile (4 panels x 16 KB) once; wave w -> panel w ----
  {
    const unsigned char* Asrc = Abase + (size_t)(by * 4 + wave) * 16384 + lane * 16;
    unsigned char* Adst = lA + wave * 16384 + lane * 16;
#pragma unroll
    for (int i = 0; i < 16; ++i)
      __builtin_amdgcn_global_load_lds(GAS(Asrc + i * 1024),
                                       LAS(Adst + i * 1024), 16, 0, 0);
  }
  __syncthreads();   // only barrier in the kernel

  union frag { i32x8 v; int4 h[2]; };

  // load both B panels for K-step uu of the tile based at `base` into dst[2]
  auto LDB = [&](frag* dst, const unsigned char* base, int uu) {
    const int off = (uu >> 1) * 4096 + (uu & 1) * 2048;
    dst[0].h[0] = *(const int4*)(base + off);
    dst[0].h[1] = *(const int4*)(base + off + 512);
    dst[1].h[0] = *(const int4*)(base + 16384 + off);
    dst[1].h[1] = *(const int4*)(base + 16384 + off + 512);
  };

  float rs[2][16];
#pragma unroll
  for (int mi = 0; mi < 2; ++mi)
#pragma unroll
    for (int rr = 0; rr < 16; ++rr) rs[mi][rr] = 0.f;

  frag fb[4][2];                       // 4-buffer rotation, depth-2 prefetch
  const unsigned char* curB =
      Bbase + (size_t)(g * 4 * 4 + pb0) * 16384 + lfo;
  LDB(fb[0], curB, 0);                 // prologue: steps 0,1 of tile 0
  LDB(fb[1], curB, 1);

  for (int t = 0; t < cnt; ++t) {
    const int ct = g * 4 + t;          // B column tile
    const unsigned char* nxtB = curB + 4 * 16384;
    const bool hasNext = (t + 1 < cnt);

    f32x16 acc[2][2];
#pragma unroll
    for (int i = 0; i < 2; ++i)
#pragma unroll
      for (int jj = 0; jj < 2; ++jj)
#pragma unroll
        for (int rr = 0; rr < 16; ++rr) acc[i][jj][rr] = 0.f;

#pragma unroll
    for (int u = 0; u < 8; ++u) {
      // depth-2 prefetch; steps 6,7 prefetch next tile's steps 0,1
      if (u < 6)            LDB(fb[(u + 2) & 3], curB, u + 2);
      else if (hasNext)     LDB(fb[(u + 2) & 3], nxtB, u - 6);

      const int ko = (u >> 1) * 4096 + (u & 1) * 2048;
      frag fa[2];
#pragma unroll
      for (int i = 0; i < 2; ++i) {
        const int oa = (pa0 + i) * 16384 + ko + lfo;
        fa[i].h[0] = *(const int4*)&lA[oa];
        fa[i].h[1] = *(const int4*)&lA[oa + 512];
      }
#pragma unroll
      for (int mi = 0; mi < 2; ++mi)
#pragma unroll
        for (int ni = 0; ni < 2; ++ni)
          acc[mi][ni] = __builtin_amdgcn_mfma_scale_f32_32x32x64_f8f6f4(
              fa[mi].v, fb[u & 3][ni].v, acc[mi][ni],
              0, 0,                    // cbsz=e4m3, blgp=e4m3
              0, 0x7F7F7F7F,           // scale_a (E8M0 1.0)
              0, 0x7F7F7F7F);          // scale_b
    }

    // per-tile epilogue: exp, rowsums in regs, colsum atomics
    // (overlaps the already-issued next-tile B prefetches)
    float cs[2] = {0.f, 0.f};
#pragma unroll
    for (int mi = 0; mi < 2; ++mi)
#pragma unroll
      for (int ni = 0; ni < 2; ++ni)
#pragma unroll
        for (int rr = 0; rr < 16; ++rr) {
          float v = exp2f(2.8853900817779268f * acc[mi][ni][rr]);
          rs[mi][rr] += v;
          cs[ni] += v;
        }
    const bool diag = (!cross) && (ct == by);
    if (!diag) {
#pragma unroll
      for (int ni = 0; ni < 2; ++ni) {
        float v = cs[ni] + __shfl_xor(cs[ni], 32, 64);
        if (half == 0)
          atomicAdd(&cptr[ct * 128 + (wave >> 1) * 64 + ni * 32 + l31], v);
      }
    }
    curB = nxtB;
  }

  // rowsum: reduce over 32 column-lanes, one atomic set per block
#pragma unroll
  for (int mi = 0; mi < 2; ++mi) {
#pragma unroll
    for (int dd = 1; dd < 32; dd <<= 1) {
#pragma unroll
      for (int rr = 0; rr < 16; ++rr) rs[mi][rr] += __shfl_xor(rs[mi][rr], dd, 64);
    }
    if (l31 == 0) {
      const int mb = by * 128 + (wave & 1) * 64 + mi * 32;
#pragma unroll
      for (int rr = 0; rr < 16; ++rr) {
        const int row = mb + (rr & 3) + 8 * (rr >> 2) + 4 * half;
        atomicAdd(&rptr[row], rs[mi][rr]);
      }
    }
  }
}

// ------- normalize -> fp8 in 32-row-panel FRAGMENT-MAJOR layout + diag dot -------
__global__ __launch_bounds__(256)
void norm_diag_kernel(const unsigned short* __restrict__ h1,
                      const unsigned short* __restrict__ h2,
                      unsigned char* __restrict__ q1,
                      unsigned char* __restrict__ q2,
                      float* __restrict__ cdiag) {
  const int wave = threadIdx.x >> 6, lane = threadIdx.x & 63;
  const int row = blockIdx.x * 4 + wave;
  const u16x8 u1 = *(const u16x8*)(h1 + (size_t)row * 512 + lane * 8);
  const u16x8 u2 = *(const u16x8*)(h2 + (size_t)row * 512 + lane * 8);
  float f1[8], f2[8], ss1 = 0.f, ss2 = 0.f;
#pragma unroll
  for (int j = 0; j < 8; ++j) {
    f1[j] = bf2f(u1[j]); ss1 += f1[j] * f1[j];
    f2[j] = bf2f(u2[j]); ss2 += f2[j] * f2[j];
  }
#pragma unroll
  for (int d = 1; d < 64; d <<= 1) {
    ss1 += __shfl_xor(ss1, d, 64);
    ss2 += __shfl_xor(ss2, d, 64);
  }
  const float inv1 = 1.0f / fmaxf(sqrtf(ss1), 1e-12f);
  const float inv2 = 1.0f / fmaxf(sqrtf(ss2), 1e-12f);
  float a[8], bb[8];
  float dot = 0.f;
#pragma unroll
  for (int j = 0; j < 8; ++j) {
    a[j] = f1[j] * inv1; bb[j] = f2[j] * inv2;
    dot += a[j] * bb[j];
  }
  int lo1 = __builtin_amdgcn_cvt_pk_fp8_f32(a[0], a[1], 0, false);
  lo1 = __builtin_amdgcn_cvt_pk_fp8_f32(a[2], a[3], lo1, true);
  int hi1 = __builtin_amdgcn_cvt_pk_fp8_f32(a[4], a[5], 0, false);
  hi1 = __builtin_amdgcn_cvt_pk_fp8_f32(a[6], a[7], hi1, true);
  int lo2 = __builtin_amdgcn_cvt_pk_fp8_f32(bb[0], bb[1], 0, false);
  lo2 = __builtin_amdgcn_cvt_pk_fp8_f32(bb[2], bb[3], lo2, true);
  int hi2 = __builtin_amdgcn_cvt_pk_fp8_f32(bb[4], bb[5], 0, false);
  hi2 = __builtin_amdgcn_cvt_pk_fp8_f32(bb[6], bb[7], hi2, true);

  // fragment-major dst: panel = row>>5, kt = c0>>6, sub = (c0>>4)&3
  const int c0 = lane * 8;
  const size_t dst = (size_t)(row >> 5) * 16384 + (c0 >> 6) * 2048
                   + ((c0 >> 4) & 3) * 512 + (row & 31) * 16 + (c0 & 15);
  *(int2*)(q1 + dst) = make_int2(lo1, hi1);
  *(int2*)(q2 + dst) = make_int2(lo2, hi2);
#pragma unroll
  for (int d = 1; d < 64; d <<= 1) dot += __shfl_xor(dot, d, 64);
  if (lane == 0) cdiag[row] = dot;
}

// ---------------- final scalar loss ----------------
__global__ __launch_bounds__(256)
void finalize_kernel(const float* __restrict__ d11, const float* __restrict__ d22,
                     const float* __restrict__ d12r, const float* __restrict__ d12c,
                     const float* __restrict__ cdiag, float* __restrict__ out) {
  const float e2 = 7.38905609893065f;
  float s = 0.f;
  for (int i = threadIdx.x; i < 8192; i += 256) {
    const float den1 = d11[i] + d12r[i] - e2;
    const float den2 = d22[i] + d12c[i] - e2;
    s += -2.0f * cdiag[i] + 0.5f * (logf(den1) + logf(den2));
  }
#pragma unroll
  for (int d = 1; d < 64; d <<= 1) s += __shfl_xor(s, d, 64);
  __shared__ float sm[4];
  if ((threadIdx.x & 63) == 0) sm[threadIdx.x >> 6] = s;
  __syncthreads();
  if (threadIdx.x == 0) out[0] = (sm[0] + sm[1] + sm[2] + sm[3]) * (1.0f / 8192.0f);
}

extern "C" void kernel_launch(void* const* d_in, const int* in_sizes, int n_in,
                              void* d_out, int out_size, void* d_ws, size_t ws_size,
                              hipStream_t stream) {
  const float* z1 = (const float*)d_in[0];
  const float* z2 = (const float*)d_in[1];
  const float* w1 = (const float*)d_in[2];
  const float* b1 = (const float*)d_in[3];
  const float* w2 = (const float*)d_in[4];
  const float* b2 = (const float*)d_in[5];
  float* out = (float*)d_out;

  const int N = 8192, D = 512;
  char* ws = (char*)d_ws;
  auto alloc = [&](size_t bytes) {
    char* p = ws; ws += (bytes + 255) & ~(size_t)255; return p;
  };
  unsigned short* z1b = (unsigned short*)alloc((size_t)N * D * 2);
  unsigned short* z2b = (unsigned short*)alloc((size_t)N * D * 2);
  unsigned short* g1  = (unsigned short*)alloc((size_t)N * D * 2);
  unsigned short* g2  = (unsigned short*)alloc((size_t)N * D * 2);
  unsigned short* w1b = (unsigned short*)alloc((size_t)D * D * 2);
  unsigned short* w2b = (unsigned short*)alloc((size_t)D * D * 2);
  float* sums  = (float*)alloc((size_t)4 * N * sizeof(float));
  float* cdiag = (float*)alloc((size_t)N * sizeof(float));
  float* d11 = sums, *d22 = sums + N, *d12r = sums + 2 * N, *d12c = sums + 3 * N;
  unsigned short* h1 = z1b;                 // stage-2 out aliases z buffers
  unsigned short* h2 = z2b;
  unsigned char* q1 = (unsigned char*)g1;   // fp8 aliases g (dead after proj2)
  unsigned char* q2 = (unsigned char*)g2;

  hipMemsetAsync(sums, 0, (size_t)4 * N * sizeof(float), stream);

  cast_all_kernel<<<dim3(8704), 256, 0, stream>>>(z1, z2, w1, w2, z1b, z2b, w1b, w2b);
  proj_kernel<0><<<dim3(512), 256, 0, stream>>>(z1b, z2b, w1b, b1, g1, g2);
  proj_kernel<1><<<dim3(512), 256, 0, stream>>>(g1, g2, w2b, b2, h1, h2);
  norm_diag_kernel<<<dim3(N / 4), 256, 0, stream>>>(h1, h2, q1, q2, cdiag);
  gram_kernel<<<dim3(2112), 256, 0, stream>>>(q1, q2, d11, d22, d12r, d12c);
  finalize_kernel<<<1, 256, 0, stream>>>(d11, d22, d12r, d12c, cdiag, out);
}

// Round 6
// 266.567 us; speedup vs baseline: 1.7722x; 1.7722x over previous
//
#include <hip/hip_runtime.h>
#include <math.h>

typedef __attribute__((ext_vector_type(8))) __bf16 bf16x8;
typedef __attribute__((ext_vector_type(4))) float f32x4;
typedef __attribute__((ext_vector_type(16))) float f32x16;
typedef __attribute__((ext_vector_type(8))) unsigned short u16x8;
typedef __attribute__((ext_vector_type(8))) int i32x8;

#define GAS(p) ((const __attribute__((address_space(1))) void*)(p))
#define LAS(p) ((__attribute__((address_space(3))) void*)(p))

__device__ __forceinline__ unsigned short f2bf(float f) {
  union { float f; unsigned int u; } v; v.f = f;
  unsigned int r = (v.u + 0x7FFFu + ((v.u >> 16) & 1u)) >> 16;
  return (unsigned short)r;
}
__device__ __forceinline__ float bf2f(unsigned short b) {
  union { unsigned int u; float f; } v; v.u = ((unsigned int)b) << 16;
  return v.f;
}

// ---------------- fused f32 -> bf16 cast for z1,z2,w1,w2 ----------------
__global__ __launch_bounds__(256) void cast_all_kernel(
    const float* __restrict__ z1, const float* __restrict__ z2,
    const float* __restrict__ w1, const float* __restrict__ w2,
    unsigned short* __restrict__ z1b, unsigned short* __restrict__ z2b,
    unsigned short* __restrict__ w1b, unsigned short* __restrict__ w2b) {
  int b = blockIdx.x;
  const float* in; unsigned short* out; int base;
  if (b < 4096)       { in = z1; out = z1b; base = b; }
  else if (b < 8192)  { in = z2; out = z2b; base = b - 4096; }
  else if (b < 8448)  { in = w1; out = w1b; base = b - 8192; }
  else                { in = w2; out = w2b; base = b - 8448; }
  int i = (base * 256 + threadIdx.x) * 4;
  float4 v = *(const float4*)(in + i);
  ushort4 o;
  o.x = f2bf(v.x); o.y = f2bf(v.y); o.z = f2bf(v.z); o.w = f2bf(v.w);
  *(ushort4*)(out + i) = o;
}

// ========== R16 proj: 64x64 tiles, 1024 blocks/launch, 32x32x16 bf16 ==========
// R15 diagnosis: proj was grid-limited (512 blocks = 2 blocks/CU, ~75 TF for
// 4.3 GFLOP). New shape: 64x64 tile, 4 waves, wave w -> 32x32 quadrant
// ((w&1),(w>>1)); acc = ONE f32x16 (16 regs) -> ~70 VGPR, fits (256,4) cap
// with no spill; grid 1024 = 4 blocks/CU. K-chunk 64, double-buffered LDS
// (4x8KB = 32 KB). LDS rows are 128 B -> 32-way bank conflict unswizzled;
// XOR-swizzle byte^=((row&7)<<4) applied BOTH sides: pre-swizzled
// global_load_lds source + swizzled ds_read (T2 + m104 both-sides rule).
// A-frag (32x32x16): lane holds A[row=l31][k=half*8+j]; B-frag symmetric
// (lane holds W[col=l31][k]); C/D: col=l31, row=(reg&3)+8*(reg>>2)+4*half.
template<int EPI>
__global__ __launch_bounds__(256, 4)
void proj_kernel(const unsigned short* __restrict__ A1,
                 const unsigned short* __restrict__ A2,
                 const unsigned short* __restrict__ W,
                 const float* __restrict__ bias,
                 unsigned short* __restrict__ C1,
                 unsigned short* __restrict__ C2) {
  __shared__ unsigned short lA[2][4096];   // [buf][64 rows x 64 k] swizzled
  __shared__ unsigned short lB[2][4096];
  const int b = blockIdx.x;
  const int which = b >> 9;
  const int r = b & 511;
  const int m0 = (r >> 3) * 64;
  const int n0 = (r & 7) * 64;
  const unsigned short* A = which ? A2 : A1;
  unsigned short* C = which ? C2 : C1;

  const int tid  = threadIdx.x;
  const int wv   = tid >> 6;
  const int lane = tid & 63;
  const int half = lane >> 5;
  const int l31  = lane & 31;

  // staging: call i covers dst bytes d = (i*4+wv)*1024 + lane*16
  // row = d>>7, c' = d&127; source col-bytes = c' ^ ((row&7)<<4)
  const int srow0 = wv * 8 + (lane >> 3);
  const int srow1 = srow0 + 32;
  const int sc0 = ((lane & 7) * 16) ^ ((srow0 & 7) << 4);
  const int sc1 = ((lane & 7) * 16) ^ ((srow1 & 7) << 4);
  const int sdst0 = wv * 1024 + lane * 16;
  const int sdst1 = sdst0 + 4096;

  const char* Ac = (const char*)A;
  const char* Wc = (const char*)W;

#define PROJ_STAGE(buf, kc)                                                    \
  do {                                                                         \
    const size_t kb = (size_t)(kc) * 128;                                      \
    __builtin_amdgcn_global_load_lds(                                          \
        GAS(Ac + (size_t)(m0 + srow0) * 1024 + kb + sc0),                      \
        LAS((char*)&lA[buf][0] + sdst0), 16, 0, 0);                            \
    __builtin_amdgcn_global_load_lds(                                          \
        GAS(Ac + (size_t)(m0 + srow1) * 1024 + kb + sc1),                      \
        LAS((char*)&lA[buf][0] + sdst1), 16, 0, 0);                            \
    __builtin_amdgcn_global_load_lds(                                          \
        GAS(Wc + (size_t)(n0 + srow0) * 1024 + kb + sc0),                      \
        LAS((char*)&lB[buf][0] + sdst0), 16, 0, 0);                            \
    __builtin_amdgcn_global_load_lds(                                          \
        GAS(Wc + (size_t)(n0 + srow1) * 1024 + kb + sc1),                      \
        LAS((char*)&lB[buf][0] + sdst1), 16, 0, 0);                            \
  } while (0)

  const int arow = (wv & 1) * 32 + l31;     // row within 64-row A tile
  const int brow = (wv >> 1) * 32 + l31;    // row (= out col) within B tile
  const int aoff = arow * 128;
  const int boff = brow * 128;
  const int aswz = (arow & 7) << 4;
  const int bswz = (brow & 7) << 4;

  f32x16 acc;
#pragma unroll
  for (int i = 0; i < 16; ++i) acc[i] = 0.f;

  PROJ_STAGE(0, 0);
  __syncthreads();

  for (int kc = 0; kc < 8; ++kc) {
    if (kc < 7) PROJ_STAGE((kc + 1) & 1, kc + 1);
    const char* bufA = (const char*)&lA[kc & 1][0];
    const char* bufB = (const char*)&lB[kc & 1][0];
#pragma unroll
    for (int s = 0; s < 4; ++s) {
      const int cb = s * 32 + half * 16;
      bf16x8 av = *(const bf16x8*)(bufA + aoff + (cb ^ aswz));
      bf16x8 bv = *(const bf16x8*)(bufB + boff + (cb ^ bswz));
      acc = __builtin_amdgcn_mfma_f32_32x32x16_bf16(av, bv, acc, 0, 0, 0);
    }
    __syncthreads();   // drains prefetch + WAR before next stage
  }
#undef PROJ_STAGE

  const int col = n0 + brow;
  const float bvs = bias[col];
#pragma unroll
  for (int reg = 0; reg < 16; ++reg) {
    const int row = m0 + (wv & 1) * 32 + (reg & 3) + 8 * (reg >> 2) + 4 * half;
    float v = acc[reg] + bvs;
    if constexpr (EPI == 0) v = (v > 0.f) ? v : expm1f(v);
    C[(size_t)row * 512 + col] = f2bf(v);
  }
}

// ========== R16 gram: R11 body verbatim + XCD-aligned block decode ==========
// R11 re-diagnosis: FETCH_SIZE 56 MB = 7x inputs -> B misses the 4 MB/XCD L2
// (old cross decode put ALL 16 B groups on every XCD); L3/HBM latency
// (~600-900 cyc) is what 2 waves/SIMD can't hide (MfmaUtil 25%).
// Fix (T1 regime): decode g = b&15, by = b>>4 so b%8 == g%8 -> each XCD
// touches only B groups {x, x+8} = 512 KB -> L2-resident. Tri grids padded
// to 1024 with early-exit dead blocks (by < 4g). Inner loop, registers,
// staging: byte-identical to R11 (112.6 us known-good).
// Grid 3072: [0,1024) tri1, [1024,2048) tri2, [2048,3072) cross.
__global__ __launch_bounds__(256, 2)
void gram_kernel(const unsigned char* __restrict__ q1,
                 const unsigned char* __restrict__ q2,
                 float* __restrict__ d11, float* __restrict__ d22,
                 float* __restrict__ d12r, float* __restrict__ d12c) {
  __shared__ unsigned char lA[65536];   // 4 panels x full K (fragment-major)

  const int b = blockIdx.x;
  const unsigned char *Abase, *Bbase;
  float *rptr, *cptr;
  int by, g, cnt;
  bool cross;
  if (b < 2048) {
    const bool first = (b < 1024);
    const int j = first ? b : b - 1024;
    g = j & 15; by = j >> 4;
    cnt = min(4, by + 1 - g * 4);
    if (cnt <= 0) return;               // dead padding block
    const unsigned char* h = first ? q1 : q2;
    Abase = h; Bbase = h;
    rptr = first ? d11 : d22; cptr = rptr;
    cross = false;
  } else {
    const int j = b - 2048;
    g = j & 15; by = j >> 4;
    Abase = q1; Bbase = q2;
    rptr = d12r; cptr = d12c;
    cnt = 4; cross = true;
  }

  const int tid  = threadIdx.x;
  const int wave = tid >> 6;
  const int lane = tid & 63;
  const int half = lane >> 5;
  const int l31  = lane & 31;
  const int pa0 = (wave & 1) * 2;
  const int pb0 = (wave >> 1) * 2;
  const int lfo = half * 1024 + l31 * 16;

  // ---- stage the full A tile (4 panels x 16 KB) once; wave w -> panel w ----
  {
    const unsigned char* Asrc = Abase + (size_t)(by * 4 + wave) * 16384 + lane * 16;
    unsigned char* Adst = lA + wave * 16384 + lane * 16;
#pragma unroll
    for (int i = 0; i < 16; ++i)
      __builtin_amdgcn_global_load_lds(GAS(Asrc + i * 1024),
                                       LAS(Adst + i * 1024), 16, 0, 0);
  }
  __syncthreads();   // only barrier in the kernel

  union frag { i32x8 v; int4 h[2]; };

  float rs[2][16];
#pragma unroll
  for (int mi = 0; mi < 2; ++mi)
#pragma unroll
    for (int rr = 0; rr < 16; ++rr) rs[mi][rr] = 0.f;

  for (int t = 0; t < cnt; ++t) {
    const int ct = g * 4 + t;   // B column tile
    const unsigned char* B0 = Bbase + (size_t)(ct * 4 + pb0) * 16384 + lfo;
    const unsigned char* B1 = B0 + 16384;

    f32x16 acc[2][2];
#pragma unroll
    for (int i = 0; i < 2; ++i)
#pragma unroll
      for (int jj = 0; jj < 2; ++jj)
#pragma unroll
        for (int rr = 0; rr < 16; ++rr) acc[i][jj][rr] = 0.f;

#pragma unroll
    for (int KT = 0; KT < 4; ++KT) {
#pragma unroll
      for (int ktl = 0; ktl < 2; ++ktl) {
        const int ko = KT * 4096 + ktl * 2048;
        frag fa[2], fb[2];
        fb[0].h[0] = *(const int4*)(B0 + ko);
        fb[0].h[1] = *(const int4*)(B0 + ko + 512);
        fb[1].h[0] = *(const int4*)(B1 + ko);
        fb[1].h[1] = *(const int4*)(B1 + ko + 512);
#pragma unroll
        for (int i = 0; i < 2; ++i) {
          const int oa = (pa0 + i) * 16384 + ko + lfo;
          fa[i].h[0] = *(const int4*)&lA[oa];
          fa[i].h[1] = *(const int4*)&lA[oa + 512];
        }
#pragma unroll
        for (int mi = 0; mi < 2; ++mi)
#pragma unroll
          for (int ni = 0; ni < 2; ++ni)
            acc[mi][ni] = __builtin_amdgcn_mfma_scale_f32_32x32x64_f8f6f4(
                fa[mi].v, fb[ni].v, acc[mi][ni],
                0, 0,                    // cbsz=e4m3, blgp=e4m3
                0, 0x7F7F7F7F,           // scale_a (E8M0 1.0)
                0, 0x7F7F7F7F);          // scale_b
      }
    }

    // per-tile epilogue: exp, accumulate rowsums in regs, colsum atomics
    float cs[2] = {0.f, 0.f};
#pragma unroll
    for (int mi = 0; mi < 2; ++mi)
#pragma unroll
      for (int ni = 0; ni < 2; ++ni)
#pragma unroll
        for (int rr = 0; rr < 16; ++rr) {
          float v = exp2f(2.8853900817779268f * acc[mi][ni][rr]);
          rs[mi][rr] += v;
          cs[ni] += v;
        }
    const bool diag = (!cross) && (ct == by);
    if (!diag) {
#pragma unroll
      for (int ni = 0; ni < 2; ++ni) {
        float v = cs[ni] + __shfl_xor(cs[ni], 32, 64);
        if (half == 0)
          atomicAdd(&cptr[ct * 128 + (wave >> 1) * 64 + ni * 32 + l31], v);
      }
    }
  }

  // rowsum: reduce over 32 column-lanes, one atomic set per block
#pragma unroll
  for (int mi = 0; mi < 2; ++mi) {
#pragma unroll
    for (int dd = 1; dd < 32; dd <<= 1) {
#pragma unroll
      for (int rr = 0; rr < 16; ++rr) rs[mi][rr] += __shfl_xor(rs[mi][rr], dd, 64);
    }
    if (l31 == 0) {
      const int mb = by * 128 + (wave & 1) * 64 + mi * 32;
#pragma unroll
      for (int rr = 0; rr < 16; ++rr) {
        const int row = mb + (rr & 3) + 8 * (rr >> 2) + 4 * half;
        atomicAdd(&rptr[row], rs[mi][rr]);
      }
    }
  }
}

// ------- normalize -> fp8 in 32-row-panel FRAGMENT-MAJOR layout + diag dot -------
__global__ __launch_bounds__(256)
void norm_diag_kernel(const unsigned short* __restrict__ h1,
                      const unsigned short* __restrict__ h2,
                      unsigned char* __restrict__ q1,
                      unsigned char* __restrict__ q2,
                      float* __restrict__ cdiag) {
  const int wave = threadIdx.x >> 6, lane = threadIdx.x & 63;
  const int row = blockIdx.x * 4 + wave;
  const u16x8 u1 = *(const u16x8*)(h1 + (size_t)row * 512 + lane * 8);
  const u16x8 u2 = *(const u16x8*)(h2 + (size_t)row * 512 + lane * 8);
  float f1[8], f2[8], ss1 = 0.f, ss2 = 0.f;
#pragma unroll
  for (int j = 0; j < 8; ++j) {
    f1[j] = bf2f(u1[j]); ss1 += f1[j] * f1[j];
    f2[j] = bf2f(u2[j]); ss2 += f2[j] * f2[j];
  }
#pragma unroll
  for (int d = 1; d < 64; d <<= 1) {
    ss1 += __shfl_xor(ss1, d, 64);
    ss2 += __shfl_xor(ss2, d, 64);
  }
  const float inv1 = 1.0f / fmaxf(sqrtf(ss1), 1e-12f);
  const float inv2 = 1.0f / fmaxf(sqrtf(ss2), 1e-12f);
  float a[8], bb[8];
  float dot = 0.f;
#pragma unroll
  for (int j = 0; j < 8; ++j) {
    a[j] = f1[j] * inv1; bb[j] = f2[j] * inv2;
    dot += a[j] * bb[j];
  }
  int lo1 = __builtin_amdgcn_cvt_pk_fp8_f32(a[0], a[1], 0, false);
  lo1 = __builtin_amdgcn_cvt_pk_fp8_f32(a[2], a[3], lo1, true);
  int hi1 = __builtin_amdgcn_cvt_pk_fp8_f32(a[4], a[5], 0, false);
  hi1 = __builtin_amdgcn_cvt_pk_fp8_f32(a[6], a[7], hi1, true);
  int lo2 = __builtin_amdgcn_cvt_pk_fp8_f32(bb[0], bb[1], 0, false);
  lo2 = __builtin_amdgcn_cvt_pk_fp8_f32(bb[2], bb[3], lo2, true);
  int hi2 = __builtin_amdgcn_cvt_pk_fp8_f32(bb[4], bb[5], 0, false);
  hi2 = __builtin_amdgcn_cvt_pk_fp8_f32(bb[6], bb[7], hi2, true);

  // fragment-major dst: panel = row>>5, kt = c0>>6, sub = (c0>>4)&3
  const int c0 = lane * 8;
  const size_t dst = (size_t)(row >> 5) * 16384 + (c0 >> 6) * 2048
                   + ((c0 >> 4) & 3) * 512 + (row & 31) * 16 + (c0 & 15);
  *(int2*)(q1 + dst) = make_int2(lo1, hi1);
  *(int2*)(q2 + dst) = make_int2(lo2, hi2);
#pragma unroll
  for (int d = 1; d < 64; d <<= 1) dot += __shfl_xor(dot, d, 64);
  if (lane == 0) cdiag[row] = dot;
}

// ---------------- final scalar loss ----------------
__global__ __launch_bounds__(256)
void finalize_kernel(const float* __restrict__ d11, const float* __restrict__ d22,
                     const float* __restrict__ d12r, const float* __restrict__ d12c,
                     const float* __restrict__ cdiag, float* __restrict__ out) {
  const float e2 = 7.38905609893065f;
  float s = 0.f;
  for (int i = threadIdx.x; i < 8192; i += 256) {
    const float den1 = d11[i] + d12r[i] - e2;
    const float den2 = d22[i] + d12c[i] - e2;
    s += -2.0f * cdiag[i] + 0.5f * (logf(den1) + logf(den2));
  }
#pragma unroll
  for (int d = 1; d < 64; d <<= 1) s += __shfl_xor(s, d, 64);
  __shared__ float sm[4];
  if ((threadIdx.x & 63) == 0) sm[threadIdx.x >> 6] = s;
  __syncthreads();
  if (threadIdx.x == 0) out[0] = (sm[0] + sm[1] + sm[2] + sm[3]) * (1.0f / 8192.0f);
}

extern "C" void kernel_launch(void* const* d_in, const int* in_sizes, int n_in,
                              void* d_out, int out_size, void* d_ws, size_t ws_size,
                              hipStream_t stream) {
  const float* z1 = (const float*)d_in[0];
  const float* z2 = (const float*)d_in[1];
  const float* w1 = (const float*)d_in[2];
  const float* b1 = (const float*)d_in[3];
  const float* w2 = (const float*)d_in[4];
  const float* b2 = (const float*)d_in[5];
  float* out = (float*)d_out;

  const int N = 8192, D = 512;
  char* ws = (char*)d_ws;
  auto alloc = [&](size_t bytes) {
    char* p = ws; ws += (bytes + 255) & ~(size_t)255; return p;
  };
  unsigned short* z1b = (unsigned short*)alloc((size_t)N * D * 2);
  unsigned short* z2b = (unsigned short*)alloc((size_t)N * D * 2);
  unsigned short* g1  = (unsigned short*)alloc((size_t)N * D * 2);
  unsigned short* g2  = (unsigned short*)alloc((size_t)N * D * 2);
  unsigned short* w1b = (unsigned short*)alloc((size_t)D * D * 2);
  unsigned short* w2b = (unsigned short*)alloc((size_t)D * D * 2);
  float* sums  = (float*)alloc((size_t)4 * N * sizeof(float));
  float* cdiag = (float*)alloc((size_t)N * sizeof(float));
  float* d11 = sums, *d22 = sums + N, *d12r = sums + 2 * N, *d12c = sums + 3 * N;
  unsigned short* h1 = z1b;                 // stage-2 out aliases z buffers
  unsigned short* h2 = z2b;
  unsigned char* q1 = (unsigned char*)g1;   // fp8 aliases g (dead after proj2)
  unsigned char* q2 = (unsigned char*)g2;

  hipMemsetAsync(sums, 0, (size_t)4 * N * sizeof(float), stream);

  cast_all_kernel<<<dim3(8704), 256, 0, stream>>>(z1, z2, w1, w2, z1b, z2b, w1b, w2b);
  proj_kernel<0><<<dim3(1024), 256, 0, stream>>>(z1b, z2b, w1b, b1, g1, g2);
  proj_kernel<1><<<dim3(1024), 256, 0, stream>>>(g1, g2, w2b, b2, h1, h2);
  norm_diag_kernel<<<dim3(N / 4), 256, 0, stream>>>(h1, h2, q1, q2, cdiag);
  gram_kernel<<<dim3(3072), 256, 0, stream>>>(q1, q2, d11, d22, d12r, d12c);
  finalize_kernel<<<1, 256, 0, stream>>>(d11, d22, d12r, d12c, cdiag, out);
}

// Round 7
// 244.694 us; speedup vs baseline: 1.9306x; 1.0894x over previous
//
#include <hip/hip_runtime.h>
#include <math.h>

typedef __attribute__((ext_vector_type(8))) __bf16 bf16x8;
typedef __attribute__((ext_vector_type(4))) float f32x4;
typedef __attribute__((ext_vector_type(16))) float f32x16;
typedef __attribute__((ext_vector_type(8))) unsigned short u16x8;
typedef __attribute__((ext_vector_type(8))) int i32x8;

#define GAS(p) ((const __attribute__((address_space(1))) void*)(p))
#define LAS(p) ((__attribute__((address_space(3))) void*)(p))

__device__ __forceinline__ unsigned short f2bf(float f) {
  union { float f; unsigned int u; } v; v.f = f;
  unsigned int r = (v.u + 0x7FFFu + ((v.u >> 16) & 1u)) >> 16;
  return (unsigned short)r;
}
__device__ __forceinline__ float bf2f(unsigned short b) {
  union { unsigned int u; float f; } v; v.u = ((unsigned int)b) << 16;
  return v.f;
}

// ---------------- fused f32 -> bf16 cast ----------------
// z1,z2 -> row-major bf16 (proj A-side stages them via gload_lds).
// w1,w2 -> FRAGMENT-MAJOR bf16 for direct 32x32x16 B-frag reads (R17):
//   addr(col,k) = (col>>5)*32768 + (k>>4)*1024 + ((k>>3)&1)*512
//               + (col&31)*16 + (k&7)*2
// so proj reads one contiguous 512B region per (panel, k-step, half) --
// coalesced, L2-resident, no LDS, no staging for W.
__global__ __launch_bounds__(256) void cast_all_kernel(
    const float* __restrict__ z1, const float* __restrict__ z2,
    const float* __restrict__ w1, const float* __restrict__ w2,
    unsigned short* __restrict__ z1b, unsigned short* __restrict__ z2b,
    unsigned short* __restrict__ w1b, unsigned short* __restrict__ w2b) {
  int b = blockIdx.x;
  if (b < 8192) {
    const float* in = (b < 4096) ? z1 : z2;
    unsigned short* out = (b < 4096) ? z1b : z2b;
    int base = (b < 4096) ? b : b - 4096;
    int i = (base * 256 + threadIdx.x) * 4;
    float4 v = *(const float4*)(in + i);
    ushort4 o;
    o.x = f2bf(v.x); o.y = f2bf(v.y); o.z = f2bf(v.z); o.w = f2bf(v.w);
    *(ushort4*)(out + i) = o;
  } else {
    const float* in = (b < 8448) ? w1 : w2;
    unsigned short* out = (b < 8448) ? w1b : w2b;
    int base = (b < 8448) ? b - 8192 : b - 8448;
    int i = (base * 256 + threadIdx.x) * 4;
    float4 v = *(const float4*)(in + i);
    unsigned int lo = (unsigned)f2bf(v.x) | ((unsigned)f2bf(v.y) << 16);
    unsigned int hi = (unsigned)f2bf(v.z) | ((unsigned)f2bf(v.w) << 16);
    const int col = i >> 9, k = i & 511;
    const size_t dst = (size_t)(col >> 5) * 32768 + (size_t)(k >> 4) * 1024
                     + (size_t)((k >> 3) & 1) * 512 + (col & 31) * 16 + (k & 7) * 2;
    *(int2*)((char*)out + dst) = make_int2((int)lo, (int)hi);
  }
}

// ========== R17 proj: 64x64 tile, A via swizzled LDS, W DIRECT from global ==========
// R16 proj staged both A and W through LDS (16 KB/chunk) with a vmcnt(0)
// drain at each chunk barrier. W (512 KB, L2-resident) never needed LDS:
// with the frag-major W layout written by cast, each wave reads its B-frag
// as one contiguous 512B chunk per step. Staged volume and drained loads
// halve; LDS -> 16 KB. A-side (swizzled stage + swizzled ds_read) unchanged
// from R16 (correctness-proven). Wave w: rows (w&1)*32, col-panel (w>>1).
template<int EPI>
__global__ __launch_bounds__(256, 4)
void proj_kernel(const unsigned short* __restrict__ A1,
                 const unsigned short* __restrict__ A2,
                 const unsigned short* __restrict__ Wf,   // fragment-major
                 const float* __restrict__ bias,
                 unsigned short* __restrict__ C1,
                 unsigned short* __restrict__ C2) {
  __shared__ unsigned short lA[2][4096];   // [buf][64 rows x 64 k] swizzled
  const int b = blockIdx.x;
  const int which = b >> 9;
  const int r = b & 511;
  const int m0 = (r >> 3) * 64;
  const int n0 = (r & 7) * 64;
  const unsigned short* A = which ? A2 : A1;
  unsigned short* C = which ? C2 : C1;

  const int tid  = threadIdx.x;
  const int wv   = tid >> 6;
  const int lane = tid & 63;
  const int half = lane >> 5;
  const int l31  = lane & 31;

  // A staging: thread covers row srow0 (and srow0+32), 16B chunk (lane&7),
  // source col-bytes XOR-swizzled so the linear LDS dst is read conflict-low.
  const int srow0 = wv * 8 + (lane >> 3);
  const int srow1 = srow0 + 32;
  const int sc0 = ((lane & 7) * 16) ^ ((srow0 & 7) << 4);
  const int sc1 = ((lane & 7) * 16) ^ ((srow1 & 7) << 4);
  const int sdst0 = wv * 1024 + lane * 16;
  const int sdst1 = sdst0 + 4096;
  const char* Ac = (const char*)A;

#define PROJ_STAGE(buf, kc)                                                    \
  do {                                                                         \
    const size_t kb = (size_t)(kc) * 128;                                      \
    __builtin_amdgcn_global_load_lds(                                          \
        GAS(Ac + (size_t)(m0 + srow0) * 1024 + kb + sc0),                      \
        LAS((char*)&lA[buf][0] + sdst0), 16, 0, 0);                            \
    __builtin_amdgcn_global_load_lds(                                          \
        GAS(Ac + (size_t)(m0 + srow1) * 1024 + kb + sc1),                      \
        LAS((char*)&lA[buf][0] + sdst1), 16, 0, 0);                            \
  } while (0)

  const int arow = (wv & 1) * 32 + l31;     // row within 64-row A tile
  const int aoff = arow * 128;
  const int aswz = (arow & 7) << 4;
  // direct W fragment base: panel (n0>>5)+(wv>>1), this lane's 16B slot
  const char* Wb = (const char*)Wf
                 + (size_t)((n0 >> 5) + (wv >> 1)) * 32768
                 + half * 512 + l31 * 16;

  f32x16 acc;
#pragma unroll
  for (int i = 0; i < 16; ++i) acc[i] = 0.f;

  PROJ_STAGE(0, 0);
  __syncthreads();

  for (int kc = 0; kc < 8; ++kc) {
    if (kc < 7) PROJ_STAGE((kc + 1) & 1, kc + 1);
    const char* bufA = (const char*)&lA[kc & 1][0];
#pragma unroll
    for (int s = 0; s < 4; ++s) {
      bf16x8 av = *(const bf16x8*)(bufA + aoff + ((s * 32 + half * 16) ^ aswz));
      bf16x8 bv = *(const bf16x8*)(Wb + (size_t)(kc * 4 + s) * 1024);
      acc = __builtin_amdgcn_mfma_f32_32x32x16_bf16(av, bv, acc, 0, 0, 0);
    }
    __syncthreads();   // drains prefetch + WAR before buffer reuse
  }
#undef PROJ_STAGE

  const int col = n0 + (wv >> 1) * 32 + l31;
  const float bvs = bias[col];
#pragma unroll
  for (int reg = 0; reg < 16; ++reg) {
    const int row = m0 + (wv & 1) * 32 + (reg & 3) + 8 * (reg >> 2) + 4 * half;
    float v = acc[reg] + bvs;
    if constexpr (EPI == 0) v = (v > 0.f) ? v : expm1f(v);
    C[(size_t)row * 512 + col] = f2bf(v);
  }
}

// ========== gram: R11 VERBATIM (known-good 112.6 us) ==========
// R16's XCD-aligned decode improved B-locality (FETCH 56->44 MB) but created
// per-XCD load imbalance (~1250 vs ~810 tiles) + 960 dead blocks ->
// Occupancy 18.6->13.6%, dur 151 us. Reverted. Balance > locality here.
// Block map: [0,544) tri1 (q1,d11), [544,1088) tri2 (q2,d22),
//            [1088,2112) cross (q1 x q2 -> d12r/d12c), b=1088+g*64+row.
// Tri rows grouped in quads: rows 4q..4q+3 have q+1 groups each;
// cum before quad q = 2q(q+1).
__global__ __launch_bounds__(256, 2)
void gram_kernel(const unsigned char* __restrict__ q1,
                 const unsigned char* __restrict__ q2,
                 float* __restrict__ d11, float* __restrict__ d22,
                 float* __restrict__ d12r, float* __restrict__ d12c) {
  __shared__ unsigned char lA[65536];   // 4 panels x full K (fragment-major)

  const int b = blockIdx.x;
  const unsigned char *Abase, *Bbase;
  float *rptr, *cptr;
  int by, g, cnt;
  bool cross;
  if (b < 1088) {
    const bool first = (b < 544);
    int j = first ? b : b - 544;
    int q = (int)((sqrtf(2.f * j + 1.f) - 1.f) * 0.5f);
    while (2 * (q + 1) * (q + 2) <= j) ++q;
    while (2 * q * (q + 1) > j) --q;
    const int w = j - 2 * q * (q + 1);
    const int dr = w / (q + 1);
    g = w - dr * (q + 1);
    by = 4 * q + dr;
    const unsigned char* h = first ? q1 : q2;
    Abase = h; Bbase = h;
    rptr = first ? d11 : d22; cptr = rptr;
    cnt = min(4, by + 1 - g * 4);
    cross = false;
  } else {
    const int j = b - 1088;
    g = j >> 6; by = j & 63;
    Abase = q1; Bbase = q2;
    rptr = d12r; cptr = d12c;
    cnt = 4; cross = true;
  }

  const int tid  = threadIdx.x;
  const int wave = tid >> 6;
  const int lane = tid & 63;
  const int half = lane >> 5;
  const int l31  = lane & 31;
  const int pa0 = (wave & 1) * 2;
  const int pb0 = (wave >> 1) * 2;
  const int lfo = half * 1024 + l31 * 16;

  // ---- stage the full A tile (4 panels x 16 KB) once; wave w -> panel w ----
  {
    const unsigned char* Asrc = Abase + (size_t)(by * 4 + wave) * 16384 + lane * 16;
    unsigned char* Adst = lA + wave * 16384 + lane * 16;
#pragma unroll
    for (int i = 0; i < 16; ++i)
      __builtin_amdgcn_global_load_lds(GAS(Asrc + i * 1024),
                                       LAS(Adst + i * 1024), 16, 0, 0);
  }
  __syncthreads();   // only barrier in the kernel

  union frag { i32x8 v; int4 h[2]; };

  float rs[2][16];
#pragma unroll
  for (int mi = 0; mi < 2; ++mi)
#pragma unroll
    for (int rr = 0; rr < 16; ++rr) rs[mi][rr] = 0.f;

  for (int t = 0; t < cnt; ++t) {
    const int ct = g * 4 + t;   // B column tile
    const unsigned char* B0 = Bbase + (size_t)(ct * 4 + pb0) * 16384 + lfo;
    const unsigned char* B1 = B0 + 16384;

    f32x16 acc[2][2];
#pragma unroll
    for (int i = 0; i < 2; ++i)
#pragma unroll
      for (int jj = 0; jj < 2; ++jj)
#pragma unroll
        for (int rr = 0; rr < 16; ++rr) acc[i][jj][rr] = 0.f;

#pragma unroll
    for (int KT = 0; KT < 4; ++KT) {
#pragma unroll
      for (int ktl = 0; ktl < 2; ++ktl) {
        const int ko = KT * 4096 + ktl * 2048;
        frag fa[2], fb[2];
        fb[0].h[0] = *(const int4*)(B0 + ko);
        fb[0].h[1] = *(const int4*)(B0 + ko + 512);
        fb[1].h[0] = *(const int4*)(B1 + ko);
        fb[1].h[1] = *(const int4*)(B1 + ko + 512);
#pragma unroll
        for (int i = 0; i < 2; ++i) {
          const int oa = (pa0 + i) * 16384 + ko + lfo;
          fa[i].h[0] = *(const int4*)&lA[oa];
          fa[i].h[1] = *(const int4*)&lA[oa + 512];
        }
#pragma unroll
        for (int mi = 0; mi < 2; ++mi)
#pragma unroll
          for (int ni = 0; ni < 2; ++ni)
            acc[mi][ni] = __builtin_amdgcn_mfma_scale_f32_32x32x64_f8f6f4(
                fa[mi].v, fb[ni].v, acc[mi][ni],
                0, 0,                    // cbsz=e4m3, blgp=e4m3
                0, 0x7F7F7F7F,           // scale_a (E8M0 1.0)
                0, 0x7F7F7F7F);          // scale_b
      }
    }

    // per-tile epilogue: exp, accumulate rowsums in regs, colsum atomics
    float cs[2] = {0.f, 0.f};
#pragma unroll
    for (int mi = 0; mi < 2; ++mi)
#pragma unroll
      for (int ni = 0; ni < 2; ++ni)
#pragma unroll
        for (int rr = 0; rr < 16; ++rr) {
          float v = exp2f(2.8853900817779268f * acc[mi][ni][rr]);
          rs[mi][rr] += v;
          cs[ni] += v;
        }
    const bool diag = (!cross) && (ct == by);
    if (!diag) {
#pragma unroll
      for (int ni = 0; ni < 2; ++ni) {
        float v = cs[ni] + __shfl_xor(cs[ni], 32, 64);
        if (half == 0)
          atomicAdd(&cptr[ct * 128 + (wave >> 1) * 64 + ni * 32 + l31], v);
      }
    }
  }

  // rowsum: reduce over 32 column-lanes, one atomic set per block
#pragma unroll
  for (int mi = 0; mi < 2; ++mi) {
#pragma unroll
    for (int dd = 1; dd < 32; dd <<= 1) {
#pragma unroll
      for (int rr = 0; rr < 16; ++rr) rs[mi][rr] += __shfl_xor(rs[mi][rr], dd, 64);
    }
    if (l31 == 0) {
      const int mb = by * 128 + (wave & 1) * 64 + mi * 32;
#pragma unroll
      for (int rr = 0; rr < 16; ++rr) {
        const int row = mb + (rr & 3) + 8 * (rr >> 2) + 4 * half;
        atomicAdd(&rptr[row], rs[mi][rr]);
      }
    }
  }
}

// ------- normalize -> fp8 in 32-row-panel FRAGMENT-MAJOR layout + diag dot -------
__global__ __launch_bounds__(256)
void norm_diag_kernel(const unsigned short* __restrict__ h1,
                      const unsigned short* __restrict__ h2,
                      unsigned char* __restrict__ q1,
                      unsigned char* __restrict__ q2,
                      float* __restrict__ cdiag) {
  const int wave = threadIdx.x >> 6, lane = threadIdx.x & 63;
  const int row = blockIdx.x * 4 + wave;
  const u16x8 u1 = *(const u16x8*)(h1 + (size_t)row * 512 + lane * 8);
  const u16x8 u2 = *(const u16x8*)(h2 + (size_t)row * 512 + lane * 8);
  float f1[8], f2[8], ss1 = 0.f, ss2 = 0.f;
#pragma unroll
  for (int j = 0; j < 8; ++j) {
    f1[j] = bf2f(u1[j]); ss1 += f1[j] * f1[j];
    f2[j] = bf2f(u2[j]); ss2 += f2[j] * f2[j];
  }
#pragma unroll
  for (int d = 1; d < 64; d <<= 1) {
    ss1 += __shfl_xor(ss1, d, 64);
    ss2 += __shfl_xor(ss2, d, 64);
  }
  const float inv1 = 1.0f / fmaxf(sqrtf(ss1), 1e-12f);
  const float inv2 = 1.0f / fmaxf(sqrtf(ss2), 1e-12f);
  float a[8], bb[8];
  float dot = 0.f;
#pragma unroll
  for (int j = 0; j < 8; ++j) {
    a[j] = f1[j] * inv1; bb[j] = f2[j] * inv2;
    dot += a[j] * bb[j];
  }
  int lo1 = __builtin_amdgcn_cvt_pk_fp8_f32(a[0], a[1], 0, false);
  lo1 = __builtin_amdgcn_cvt_pk_fp8_f32(a[2], a[3], lo1, true);
  int hi1 = __builtin_amdgcn_cvt_pk_fp8_f32(a[4], a[5], 0, false);
  hi1 = __builtin_amdgcn_cvt_pk_fp8_f32(a[6], a[7], hi1, true);
  int lo2 = __builtin_amdgcn_cvt_pk_fp8_f32(bb[0], bb[1], 0, false);
  lo2 = __builtin_amdgcn_cvt_pk_fp8_f32(bb[2], bb[3], lo2, true);
  int hi2 = __builtin_amdgcn_cvt_pk_fp8_f32(bb[4], bb[5], 0, false);
  hi2 = __builtin_amdgcn_cvt_pk_fp8_f32(bb[6], bb[7], hi2, true);

  // fragment-major dst: panel = row>>5, kt = c0>>6, sub = (c0>>4)&3
  const int c0 = lane * 8;
  const size_t dst = (size_t)(row >> 5) * 16384 + (c0 >> 6) * 2048
                   + ((c0 >> 4) & 3) * 512 + (row & 31) * 16 + (c0 & 15);
  *(int2*)(q1 + dst) = make_int2(lo1, hi1);
  *(int2*)(q2 + dst) = make_int2(lo2, hi2);
#pragma unroll
  for (int d = 1; d < 64; d <<= 1) dot += __shfl_xor(dot, d, 64);
  if (lane == 0) cdiag[row] = dot;
}

// ---------------- final scalar loss ----------------
__global__ __launch_bounds__(256)
void finalize_kernel(const float* __restrict__ d11, const float* __restrict__ d22,
                     const float* __restrict__ d12r, const float* __restrict__ d12c,
                     const float* __restrict__ cdiag, float* __restrict__ out) {
  const float e2 = 7.38905609893065f;
  float s = 0.f;
  for (int i = threadIdx.x; i < 8192; i += 256) {
    const float den1 = d11[i] + d12r[i] - e2;
    const float den2 = d22[i] + d12c[i] - e2;
    s += -2.0f * cdiag[i] + 0.5f * (logf(den1) + logf(den2));
  }
#pragma unroll
  for (int d = 1; d < 64; d <<= 1) s += __shfl_xor(s, d, 64);
  __shared__ float sm[4];
  if ((threadIdx.x & 63) == 0) sm[threadIdx.x >> 6] = s;
  __syncthreads();
  if (threadIdx.x == 0) out[0] = (sm[0] + sm[1] + sm[2] + sm[3]) * (1.0f / 8192.0f);
}

extern "C" void kernel_launch(void* const* d_in, const int* in_sizes, int n_in,
                              void* d_out, int out_size, void* d_ws, size_t ws_size,
                              hipStream_t stream) {
  const float* z1 = (const float*)d_in[0];
  const float* z2 = (const float*)d_in[1];
  const float* w1 = (const float*)d_in[2];
  const float* b1 = (const float*)d_in[3];
  const float* w2 = (const float*)d_in[4];
  const float* b2 = (const float*)d_in[5];
  float* out = (float*)d_out;

  const int N = 8192, D = 512;
  char* ws = (char*)d_ws;
  auto alloc = [&](size_t bytes) {
    char* p = ws; ws += (bytes + 255) & ~(size_t)255; return p;
  };
  unsigned short* z1b = (unsigned short*)alloc((size_t)N * D * 2);
  unsigned short* z2b = (unsigned short*)alloc((size_t)N * D * 2);
  unsigned short* g1  = (unsigned short*)alloc((size_t)N * D * 2);
  unsigned short* g2  = (unsigned short*)alloc((size_t)N * D * 2);
  unsigned short* w1b = (unsigned short*)alloc((size_t)D * D * 2);
  unsigned short* w2b = (unsigned short*)alloc((size_t)D * D * 2);
  float* sums  = (float*)alloc((size_t)4 * N * sizeof(float));
  float* cdiag = (float*)alloc((size_t)N * sizeof(float));
  float* d11 = sums, *d22 = sums + N, *d12r = sums + 2 * N, *d12c = sums + 3 * N;
  unsigned short* h1 = z1b;                 // stage-2 out aliases z buffers
  unsigned short* h2 = z2b;
  unsigned char* q1 = (unsigned char*)g1;   // fp8 aliases g (dead after proj2)
  unsigned char* q2 = (unsigned char*)g2;

  hipMemsetAsync(sums, 0, (size_t)4 * N * sizeof(float), stream);

  cast_all_kernel<<<dim3(8704), 256, 0, stream>>>(z1, z2, w1, w2, z1b, z2b, w1b, w2b);
  proj_kernel<0><<<dim3(1024), 256, 0, stream>>>(z1b, z2b, w1b, b1, g1, g2);
  proj_kernel<1><<<dim3(1024), 256, 0, stream>>>(g1, g2, w2b, b2, h1, h2);
  norm_diag_kernel<<<dim3(N / 4), 256, 0, stream>>>(h1, h2, q1, q2, cdiag);
  gram_kernel<<<dim3(2112), 256, 0, stream>>>(q1, q2, d11, d22, d12r, d12c);
  finalize_kernel<<<1, 256, 0, stream>>>(d11, d22, d12r, d12c, cdiag, out);
}